// Round 5
// baseline (6465.632 us; speedup 1.0000x reference)
//
#include <hip/hip_runtime.h>
#include <hip/hip_fp16.h>

#define DEVINL __device__ __forceinline__

static constexpr int Bn = 2048;
static constexpr int Sn = 256;
static constexpr long long BSn = (long long)Bn * Sn;  // 524288

typedef _Float16 h2v __attribute__((ext_vector_type(2)));
typedef _Float16 half8 __attribute__((ext_vector_type(8)));
typedef float floatx4 __attribute__((ext_vector_type(4)));

DEVINL float dot2(unsigned int a, unsigned int b, float c) {
#if __has_builtin(__builtin_amdgcn_fdot2)
    return __builtin_amdgcn_fdot2(__builtin_bit_cast(h2v, a), __builtin_bit_cast(h2v, b), c, false);
#else
    __half2 ha = __builtin_bit_cast(__half2, a);
    __half2 hb = __builtin_bit_cast(__half2, b);
    return c + __low2float(ha) * __low2float(hb) + __high2float(ha) * __high2float(hb);
#endif
}
DEVINL unsigned int packh2(float a, float b) {
    __half2 h = __floats2half2_rn(a, b);
    return __builtin_bit_cast(unsigned int, h);
}
DEVINL float h16tof(unsigned short u) { return (float)__builtin_bit_cast(_Float16, u); }
DEVINL unsigned short f2h16(float f) { return __builtin_bit_cast(unsigned short, (_Float16)f); }
DEVINL float sigmoidf_(float x) { return 1.0f / (1.0f + __expf(-x)); }
DEVINL float tanhf_(float x) { return 2.0f / (1.0f + __expf(-2.0f * x)) - 1.0f; }

// encoder-weight overlay offsets (u32) inside s_mem; dead after phase 0
enum {
    O_PE1 = 0,        // [64][12]  pe_w1^T pairs (21 pad 24)
    O_PE2 = 768,      // [64][32]  pe_w2^T pairs
    O_EE1 = 2816,     // [32][8]   ee_w1^T pairs (13 pad 16)
    O_EE2 = 3072,     // [16][16]  ee_w2^T pairs
    O_CB1 = 3328,     // [128][32] cb_w1^T pairs (63 pad 64)
    O_CB2 = 7424,     // [64][64]  cb_w2^T pairs
    O_BIAS = 11520    // 400 floats
};
// s_mem region offsets (u32)
enum {
    O_XC = 0,         // x-chunk: [64][136] u16 = 4352 u32 (row pad 136 halves kills read conflicts)
    O_WXC = 4352,     // wx-chunk: [64][256] u16 = 8192 u32
    O_HH = 12544,     // h-history: [64][32] u32 (swizzled pairs)
    N_MEM = 14592
};

__global__ __launch_bounds__(512)
void k_fused(
    const float* __restrict__ self_obs, const float* __restrict__ tm_obs,
    const float* __restrict__ en_obs, const float* __restrict__ cp_obs,
    const int* __restrict__ role_ids,
    const float* __restrict__ pe_w1, const float* __restrict__ pe_b1,
    const float* __restrict__ pe_w2, const float* __restrict__ pe_b2,
    const float* __restrict__ role_emb,
    const float* __restrict__ ee_w1, const float* __restrict__ ee_b1,
    const float* __restrict__ ee_w2, const float* __restrict__ ee_b2,
    const float* __restrict__ cb_w1, const float* __restrict__ cb_b1,
    const float* __restrict__ cb_w2, const float* __restrict__ cb_b2,
    const float* __restrict__ ih_w, const float* __restrict__ ih_b,
    const float* __restrict__ hh_w, const float* __restrict__ hh_b,
    const float* __restrict__ th_w, const float* __restrict__ th_b,
    const float* __restrict__ an_w, const float* __restrict__ an_b,
    const float* __restrict__ sh_w, const float* __restrict__ sh_b,
    const float* __restrict__ bo_w, const float* __restrict__ bo_b,
    const float* __restrict__ logstd, float* __restrict__ out)
{
    __shared__ __align__(16) unsigned int s_mem[N_MEM];  // 58.4 KB multi-use
    __shared__ __align__(16) unsigned int s_h32[32];     // current h as f16 pairs
    __shared__ float s_g[192];
    __shared__ unsigned int s_hw[192];
    __shared__ float s_hb[8];

    unsigned short* s_xc16 = (unsigned short*)(s_mem + O_XC);
    unsigned short* s_wxc16 = (unsigned short*)(s_mem + O_WXC);
    unsigned int* s_hh = s_mem + O_HH;

    const int t = threadIdx.x;
    const int b = blockIdx.x;

    // ---------------- weight staging (f32 -> f16 pairs, transposed+padded) ----------------
    for (int i = t; i < 768; i += 512) {
        int o = i / 12, m = i % 12, k0 = 2 * m, k1 = k0 + 1;
        float a = (k0 < 21) ? pe_w1[k0 * 64 + o] : 0.f;
        float c = (k1 < 21) ? pe_w1[k1 * 64 + o] : 0.f;
        s_mem[O_PE1 + i] = packh2(a, c);
    }
    for (int i = t; i < 2048; i += 512) {
        int o = i >> 5, m = i & 31;
        s_mem[O_PE2 + i] = packh2(pe_w2[(2 * m) * 64 + o], pe_w2[(2 * m + 1) * 64 + o]);
    }
    if (t < 256) {
        int i = t;
        int o = i >> 3, m = i & 7, k0 = 2 * m, k1 = k0 + 1;
        float a = (k0 < 13) ? ee_w1[k0 * 32 + o] : 0.f;
        float c = (k1 < 13) ? ee_w1[k1 * 32 + o] : 0.f;
        s_mem[O_EE1 + i] = packh2(a, c);
    } else {
        int i = t - 256;
        int o = i >> 4, m = i & 15;
        s_mem[O_EE2 + i] = packh2(ee_w2[(2 * m) * 16 + o], ee_w2[(2 * m + 1) * 16 + o]);
    }
    for (int i = t; i < 4096; i += 512) {
        int o = i >> 5, m = i & 31, k0 = 2 * m, k1 = k0 + 1;
        float a = (k0 < 63) ? cb_w1[k0 * 128 + o] : 0.f;
        float c = (k1 < 63) ? cb_w1[k1 * 128 + o] : 0.f;
        s_mem[O_CB1 + i] = packh2(a, c);
    }
    for (int i = t; i < 4096; i += 512) {
        int o = i >> 6, m = i & 63;
        s_mem[O_CB2 + i] = packh2(cb_w2[(2 * m) * 64 + o], cb_w2[(2 * m + 1) * 64 + o]);
    }
    float* bias = (float*)(s_mem + O_BIAS);
    if (t < 64) bias[t] = pe_b1[t];
    if (t < 64) bias[64 + t] = pe_b2[t];
    if (t < 32) bias[128 + t] = ee_b1[t];
    if (t < 16) bias[160 + t] = ee_b2[t];
    if (t < 128) bias[176 + t] = cb_b1[t];
    if (t < 64) bias[304 + t] = cb_b2[t];
    if (t < 32) bias[368 + t] = role_emb[t];
    if (t < 32)        s_hw[t]        = packh2(th_w[2 * t], th_w[2 * t + 1]);
    else if (t < 64)  { int m = t - 32;  s_hw[32 + m]  = packh2(an_w[2 * m], an_w[2 * m + 1]); }
    else if (t < 96)  { int m = t - 64;  s_hw[64 + m]  = packh2(sh_w[4 * m], sh_w[4 * m + 2]); }
    else if (t < 128) { int m = t - 96;  s_hw[96 + m]  = packh2(sh_w[4 * m + 1], sh_w[4 * m + 3]); }
    else if (t < 160) { int m = t - 128; s_hw[128 + m] = packh2(bo_w[4 * m], bo_w[4 * m + 2]); }
    else if (t < 192) { int m = t - 160; s_hw[160 + m] = packh2(bo_w[4 * m + 1], bo_w[4 * m + 3]); }
    if (t == 0) {
        s_hb[0] = th_b[0]; s_hb[1] = an_b[0];
        s_hb[2] = sh_b[0]; s_hb[3] = sh_b[1];
        s_hb[4] = bo_b[0]; s_hb[5] = bo_b[1];
        s_hb[6] = fmaxf(__expf(logstd[0]), 0.05f);
        s_hb[7] = fmaxf(__expf(logstd[1]), 0.05f);
    }
    if (t < 32) s_h32[t] = 0u;  // h0 = 0
    __syncthreads();

    // ---------------- phase 0: encoders; pair (2s, 2s+1) handles step s ----------------
    unsigned int resp[32];  // X[s] pilot half (e==1 threads)
    unsigned int resc[16];  // X[s] cmd quarter (both threads)
    {
        const int s = t >> 1;
        const int e = t & 1;
        const long long row = (long long)b * Sn + s;

        unsigned int cpp[32];
        if (e == 0) {
            float lat[32];
            #pragma unroll 1
            for (int src = 0; src < 3; src++) {
                const float* xp = (src == 0) ? (tm_obs + row * 13) : (en_obs + row * 26 + (src - 1) * 13);
                unsigned int xpr[8];
                #pragma unroll
                for (int m = 0; m < 8; m++) {
                    int k0 = 2 * m, k1 = k0 + 1;
                    xpr[m] = packh2((k0 < 13) ? xp[k0] : 0.f, (k1 < 13) ? xp[k1] : 0.f);
                }
                unsigned int e1[16];
                #pragma unroll
                for (int o2 = 0; o2 < 16; o2++) {
                    float a0 = bias[128 + 2 * o2], a1 = bias[128 + 2 * o2 + 1];
                    const unsigned int* w0 = s_mem + O_EE1 + (2 * o2) * 8;
                    #pragma unroll
                    for (int m = 0; m < 8; m++) { a0 = dot2(xpr[m], w0[m], a0); a1 = dot2(xpr[m], w0[8 + m], a1); }
                    e1[o2] = packh2(fmaxf(a0, 0.f), fmaxf(a1, 0.f));
                }
                #pragma unroll
                for (int o = 0; o < 16; o++) {
                    float a0 = bias[160 + o];
                    const unsigned int* w0 = s_mem + O_EE2 + o * 16;
                    #pragma unroll
                    for (int m = 0; m < 16; m++) a0 = dot2(e1[m], w0[m], a0);
                    if (src == 0) lat[o] = a0;
                    else if (src == 1) lat[16 + o] = a0;
                    else lat[16 + o] = fmaxf(lat[16 + o], a0);
                }
            }
            const float* sp = self_obs + row * 15;
            const int rid = role_ids[row];
            const float* rvec = bias + 368 + rid * 16;
            #pragma unroll
            for (int m = 0; m < 32; m++) {
                int k0 = 2 * m, k1 = k0 + 1;
                float a = (k0 < 15) ? sp[k0] : (k0 < 31) ? lat[k0 - 15] : (k0 < 47) ? lat[16 + k0 - 31] : rvec[k0 - 47];
                float c = (k1 < 15) ? sp[k1] : (k1 < 31) ? lat[k1 - 15] : (k1 < 47) ? lat[16 + k1 - 31]
                                                                       : (k1 < 63) ? rvec[k1 - 47] : 0.f;
                cpp[m] = packh2(a, c);
            }
        }
        #pragma unroll
        for (int m = 0; m < 32; m++) {
            unsigned int v = __shfl_xor(cpp[m], 1);
            if (e) cpp[m] = v;
        }
        unsigned int c1h[32];
        #pragma unroll
        for (int o2 = 0; o2 < 32; o2++) {
            const int o2g = e * 32 + o2;
            float a0 = bias[176 + 2 * o2g], a1 = bias[176 + 2 * o2g + 1];
            const unsigned int* w0 = s_mem + O_CB1 + (2 * o2g) * 32;
            #pragma unroll
            for (int m = 0; m < 32; m++) { a0 = dot2(cpp[m], w0[m], a0); a1 = dot2(cpp[m], w0[32 + m], a1); }
            c1h[o2] = packh2(fmaxf(a0, 0.f), fmaxf(a1, 0.f));
        }
        unsigned int c1o[32];
        #pragma unroll
        for (int m = 0; m < 32; m++) c1o[m] = __shfl_xor(c1h[m], 1);
        {
            const int ob = e * 32;
            const int tb = 32 - ob;
            #pragma unroll
            for (int o2 = 0; o2 < 16; o2++) {
                const int o2g = e * 16 + o2;
                float a0 = bias[304 + 2 * o2g], a1 = bias[304 + 2 * o2g + 1];
                const unsigned int* w0 = s_mem + O_CB2 + (2 * o2g) * 64;
                #pragma unroll
                for (int m = 0; m < 32; m++) { a0 = dot2(c1h[m], w0[ob + m], a0); a1 = dot2(c1h[m], w0[64 + ob + m], a1); }
                #pragma unroll
                for (int m = 0; m < 32; m++) { a0 = dot2(c1o[m], w0[tb + m], a0); a1 = dot2(c1o[m], w0[64 + tb + m], a1); }
                resc[o2] = packh2(fmaxf(a0, 0.f), fmaxf(a1, 0.f));
            }
        }
        if (e == 1) {
            unsigned int inp[12];
            {
                const float* sp = self_obs + row * 15;
                const float* cp = cp_obs + row * 6;
                #pragma unroll
                for (int m = 0; m < 12; m++) {
                    int k0 = 2 * m, k1 = k0 + 1;
                    float a = (k0 < 15) ? sp[k0] : ((k0 < 21) ? cp[k0 - 15] : 0.f);
                    float c = (k1 < 15) ? sp[k1] : ((k1 < 21) ? cp[k1 - 15] : 0.f);
                    inp[m] = packh2(a, c);
                }
            }
            unsigned int r1p[32];
            #pragma unroll
            for (int o2 = 0; o2 < 32; o2++) {
                float a0 = bias[2 * o2], a1 = bias[2 * o2 + 1];
                const unsigned int* w0 = s_mem + O_PE1 + (2 * o2) * 12;
                #pragma unroll
                for (int m = 0; m < 12; m++) { a0 = dot2(inp[m], w0[m], a0); a1 = dot2(inp[m], w0[12 + m], a1); }
                r1p[o2] = packh2(fmaxf(a0, 0.f), fmaxf(a1, 0.f));
            }
            #pragma unroll
            for (int o2 = 0; o2 < 32; o2++) {
                float a0 = bias[64 + 2 * o2], a1 = bias[64 + 2 * o2 + 1];
                const unsigned int* w0 = s_mem + O_PE2 + (2 * o2) * 32;
                #pragma unroll
                for (int m = 0; m < 32; m++) { a0 = dot2(r1p[m], w0[m], a0); a1 = dot2(r1p[m], w0[32 + m], a1); }
                resp[o2] = packh2(fmaxf(a0, 0.f), fmaxf(a1, 0.f));
            }
        }
    }
    // NOTE: no barrier yet — weights stay valid until each thread reaches the chunk-0 barrier.

    // ---------------- per-wave W_ih MFMA B-fragments + LSTM hh weights ----------------
    const int lane = t & 63;
    const int wv = t >> 6;
    half8 bfr[2][4];
    #pragma unroll
    for (int ct = 0; ct < 2; ct++) {
        #pragma unroll
        for (int kt = 0; kt < 4; kt++) {
            half8 v;
            const int gc = wv * 32 + ct * 16 + (lane & 15);
            const int kb = kt * 32 + (lane >> 4) * 8;
            #pragma unroll
            for (int j = 0; j < 8; j++) v[j] = (_Float16)ih_w[(kb + j) * 256 + gc];
            bfr[ct][kt] = v;
        }
    }
    const int g = t >> 1;
    const int e = t & 1;
    const int grp = g >> 6;
    unsigned int whh[16];
    #pragma unroll
    for (int j = 0; j < 16; j++) {
        int m = e * 16 + j;
        whh[j] = packh2(hh_w[(2 * m) * 256 + g], hh_w[(2 * m + 1) * 256 + g]);
    }
    const float bias_t = (e == 0) ? (ih_b[g] + hh_b[g]) : 0.f;

    // ---------------- chunked: MFMA wx -> sequential LSTM -> heads ----------------
    float c = 0.f, h = 0.f, i_act = 0.f;
    #pragma unroll 1
    for (int ck = 0; ck < 4; ck++) {
        // write this chunk's X rows (from phase-0 regs)
        if ((g >> 6) == ck) {           // s = g in [64*ck, 64*ck+64)
            const int r = g & 63;
            unsigned int* xr = (unsigned int*)(s_xc16 + r * 136);
            if (e == 1) {
                #pragma unroll
                for (int j = 0; j < 32; j++) xr[j] = resp[j];
                #pragma unroll
                for (int j = 0; j < 16; j++) xr[48 + j] = resc[j];
            } else {
                #pragma unroll
                for (int j = 0; j < 16; j++) xr[32 + j] = resc[j];
            }
        }
        __syncthreads();  // x-chunk ready; also (ck==0) all phase-0 weight reads done

        // MFMA: wx[64][256] for this chunk; wave wv owns gates [32wv, 32wv+32)
        #pragma unroll 1
        for (int rt = 0; rt < 4; rt++) {
            half8 afr[4];
            const int arow = rt * 16 + (lane & 15);
            #pragma unroll
            for (int kt = 0; kt < 4; kt++)
                afr[kt] = *(const half8*)(s_xc16 + arow * 136 + kt * 32 + (lane >> 4) * 8);
            #pragma unroll
            for (int ct = 0; ct < 2; ct++) {
                floatx4 d = {0.f, 0.f, 0.f, 0.f};
                #pragma unroll
                for (int kt = 0; kt < 4; kt++)
                    d = __builtin_amdgcn_mfma_f32_16x16x32_f16(afr[kt], bfr[ct][kt], d, 0, 0, 0);
                const int wcol = wv * 32 + ct * 16 + (lane & 15);
                const int row0 = rt * 16 + (lane >> 4) * 4;
                #pragma unroll
                for (int r = 0; r < 4; r++)
                    s_wxc16[(row0 + r) * 256 + wcol] = f2h16(d[r]);
            }
        }
        __syncthreads();  // wx chunk ready

        // sequential LSTM over the chunk
        #pragma unroll 1
        for (int sl = 0; sl < 64; sl++) {
            float xv = h16tof(s_wxc16[sl * 256 + g]);
            float acc = (e == 0) ? (bias_t + xv) : 0.f;
            const uint4* hq = reinterpret_cast<const uint4*>(s_h32) + e * 4;
            #pragma unroll
            for (int q = 0; q < 4; q++) {
                uint4 hv = hq[q];
                acc = dot2(hv.x, whh[4 * q + 0], acc);
                acc = dot2(hv.y, whh[4 * q + 1], acc);
                acc = dot2(hv.z, whh[4 * q + 2], acc);
                acc = dot2(hv.w, whh[4 * q + 3], acc);
            }
            float tot = acc + __shfl_xor(acc, 1);
            if (e == 0) {
                float act = (grp == 2) ? tanhf_(tot) : sigmoidf_(tot);
                if (grp == 0) i_act = act; else s_g[g - 64] = act;
            }
            __syncthreads();
            if (e == 0 && g < 64) {
                float f_ = s_g[g], g_ = s_g[64 + g], o_ = s_g[128 + g];
                c = f_ * c + i_act * g_;
                h = o_ * tanhf_(c);
                float hnext = __shfl_down(h, 2);
                if ((g & 1) == 0) {
                    unsigned int hp = packh2(h, hnext);
                    s_h32[g >> 1] = hp;
                    s_hh[sl * 32 + (((g >> 1) + sl) & 31)] = hp;  // swizzled history
                }
            }
            __syncthreads();
        }

        // heads for this chunk: thread -> (step sl = wv*8 + (lane>>3), pair-block m0)
        {
            const int sl = wv * 8 + (lane >> 3);
            const int m0 = (lane & 7) * 4;
            const int j0 = lane & 7;
            float ath = 0.f, aan = 0.f, as0 = 0.f, as1 = 0.f, ab0 = 0.f, ab1 = 0.f;
            #pragma unroll
            for (int j = 0; j < 4; j++) {
                int m = m0 + j;
                unsigned int hv = s_hh[sl * 32 + ((m + sl) & 31)];
                ath = dot2(hv, s_hw[m], ath);
                aan = dot2(hv, s_hw[32 + m], aan);
                as0 = dot2(hv, s_hw[64 + m], as0);
                as1 = dot2(hv, s_hw[96 + m], as1);
                ab0 = dot2(hv, s_hw[128 + m], ab0);
                ab1 = dot2(hv, s_hw[160 + m], ab1);
            }
            #pragma unroll
            for (int d = 1; d < 8; d <<= 1) {
                ath += __shfl_xor(ath, d); aan += __shfl_xor(aan, d);
                as0 += __shfl_xor(as0, d); as1 += __shfl_xor(as1, d);
                ab0 += __shfl_xor(ab0, d); ab1 += __shfl_xor(ab1, d);
            }
            long long row = (long long)b * Sn + ck * 64 + sl;
            if (j0 == 0)      out[row] = sigmoidf_(ath + s_hb[0]);
            else if (j0 == 1) out[BSn + row] = tanhf_(aan + s_hb[1]);
            else if (j0 == 2) out[2 * BSn + 2 * row] = s_hb[6];
            else if (j0 == 3) out[2 * BSn + 2 * row + 1] = s_hb[7];
            else if (j0 == 4) out[4 * BSn + 2 * row] = as0 + s_hb[2];
            else if (j0 == 5) out[4 * BSn + 2 * row + 1] = as1 + s_hb[3];
            else if (j0 == 6) out[6 * BSn + 2 * row] = ab0 + s_hb[4];
            else              out[6 * BSn + 2 * row + 1] = ab1 + s_hb[5];
        }
    }

    if (e == 0 && g < 64) {
        float* hn = out + 8 * BSn;
        float* cn = hn + (long long)Bn * 64;
        hn[(long long)b * 64 + g] = h;
        cn[(long long)b * 64 + g] = c;
    }
}

extern "C" void kernel_launch(void* const* d_in, const int* in_sizes, int n_in,
                              void* d_out, int out_size, void* d_ws, size_t ws_size,
                              hipStream_t stream)
{
    (void)in_sizes; (void)n_in; (void)out_size; (void)d_ws; (void)ws_size;
    k_fused<<<Bn, 512, 0, stream>>>(
        (const float*)d_in[0], (const float*)d_in[1], (const float*)d_in[2],
        (const float*)d_in[3], (const int*)d_in[4],
        (const float*)d_in[5], (const float*)d_in[6], (const float*)d_in[7], (const float*)d_in[8],
        (const float*)d_in[9],
        (const float*)d_in[10], (const float*)d_in[11], (const float*)d_in[12], (const float*)d_in[13],
        (const float*)d_in[14], (const float*)d_in[15], (const float*)d_in[16], (const float*)d_in[17],
        (const float*)d_in[18], (const float*)d_in[19], (const float*)d_in[20], (const float*)d_in[21],
        (const float*)d_in[22], (const float*)d_in[23], (const float*)d_in[24], (const float*)d_in[25],
        (const float*)d_in[26], (const float*)d_in[27], (const float*)d_in[28], (const float*)d_in[29],
        (const float*)d_in[30], (float*)d_out);
}

// Round 6
// 6171.265 us; speedup vs baseline: 1.0477x; 1.0477x over previous
//
#include <hip/hip_runtime.h>
#include <hip/hip_fp16.h>

#define DEVINL __device__ __forceinline__

static constexpr int Bn = 2048;
static constexpr int Sn = 256;
static constexpr long long BSn = (long long)Bn * Sn;  // 524288

typedef _Float16 h2v __attribute__((ext_vector_type(2)));

DEVINL float dot2(unsigned int a, unsigned int b, float c) {
#if __has_builtin(__builtin_amdgcn_fdot2)
    return __builtin_amdgcn_fdot2(__builtin_bit_cast(h2v, a), __builtin_bit_cast(h2v, b), c, false);
#else
    __half2 ha = __builtin_bit_cast(__half2, a);
    __half2 hb = __builtin_bit_cast(__half2, b);
    return c + __low2float(ha) * __low2float(hb) + __high2float(ha) * __high2float(hb);
#endif
}
DEVINL unsigned int packh2(float a, float b) {
    __half2 h = __floats2half2_rn(a, b);
    return __builtin_bit_cast(unsigned int, h);
}
DEVINL float sigmoidf_(float x) { return 1.0f / (1.0f + __expf(-x)); }
DEVINL float tanhf_(float x) { return 2.0f / (1.0f + __expf(-2.0f * x)) - 1.0f; }

// s_tile u32-offset map (weights overlay; row_tile overwrites them after phase 0)
enum {
    O_PE1 = 0,        // [64][12]  pe_w1^T pairs (21 pad 24)
    O_PE2 = 768,      // [64][32]  pe_w2^T pairs
    O_EE1 = 2816,     // [32][8]   ee_w1^T pairs (13 pad 16)
    O_EE2 = 3072,     // [16][16]  ee_w2^T pairs
    O_CB1 = 3328,     // [128][32] cb_w1^T pairs (63 pad 64)
    O_CB2 = 7424,     // [64][64]  cb_w2^T pairs
    O_BIAS = 11520    // 400 floats: pe_b1(64) pe_b2(64) ee_b1(32) ee_b2(16) cb_b1(128) cb_b2(64) role(32)
};

// 512 threads = 8 waves = 2 waves/EU per block. Pin 4 waves/EU (= 2 blocks/CU
// with our 66 KB LDS) -> VGPR cap 512/4 = 128, which the R4 structure fits.
// (R4's __launch_bounds__(512,4) made the allocator target 64 VGPRs -> spill storm.)
__global__ __launch_bounds__(512) __attribute__((amdgpu_waves_per_eu(4, 4)))
void k_fused(
    const float* __restrict__ self_obs, const float* __restrict__ tm_obs,
    const float* __restrict__ en_obs, const float* __restrict__ cp_obs,
    const int* __restrict__ role_ids,
    const float* __restrict__ pe_w1, const float* __restrict__ pe_b1,
    const float* __restrict__ pe_w2, const float* __restrict__ pe_b2,
    const float* __restrict__ role_emb,
    const float* __restrict__ ee_w1, const float* __restrict__ ee_b1,
    const float* __restrict__ ee_w2, const float* __restrict__ ee_b2,
    const float* __restrict__ cb_w1, const float* __restrict__ cb_b1,
    const float* __restrict__ cb_w2, const float* __restrict__ cb_b2,
    const float* __restrict__ ih_w, const float* __restrict__ ih_b,
    const float* __restrict__ hh_w, const float* __restrict__ hh_b,
    const float* __restrict__ th_w, const float* __restrict__ th_b,
    const float* __restrict__ an_w, const float* __restrict__ an_b,
    const float* __restrict__ sh_w, const float* __restrict__ sh_b,
    const float* __restrict__ bo_w, const float* __restrict__ bo_b,
    const float* __restrict__ logstd, float* __restrict__ out)
{
    __shared__ __align__(16) unsigned int s_tile[Sn * 64];  // 64 KB: weights, then row tile
    __shared__ __align__(16) unsigned int s_h32[32];        // h as f16 pairs
    __shared__ float s_g[192];
    __shared__ unsigned int s_hw[192];
    __shared__ float s_hb[8];

    const int t = threadIdx.x;
    const int b = blockIdx.x;

    // ---------------- weight staging (f32 -> f16 pairs, transposed+padded) ----------------
    for (int i = t; i < 768; i += 512) {
        int o = i / 12, m = i % 12, k0 = 2 * m, k1 = k0 + 1;
        float a = (k0 < 21) ? pe_w1[k0 * 64 + o] : 0.f;
        float c = (k1 < 21) ? pe_w1[k1 * 64 + o] : 0.f;
        s_tile[O_PE1 + i] = packh2(a, c);
    }
    for (int i = t; i < 2048; i += 512) {
        int o = i >> 5, m = i & 31;
        s_tile[O_PE2 + i] = packh2(pe_w2[(2 * m) * 64 + o], pe_w2[(2 * m + 1) * 64 + o]);
    }
    if (t < 256) {
        int i = t;
        int o = i >> 3, m = i & 7, k0 = 2 * m, k1 = k0 + 1;
        float a = (k0 < 13) ? ee_w1[k0 * 32 + o] : 0.f;
        float c = (k1 < 13) ? ee_w1[k1 * 32 + o] : 0.f;
        s_tile[O_EE1 + i] = packh2(a, c);
    } else {
        int i = t - 256;
        int o = i >> 4, m = i & 15;
        s_tile[O_EE2 + i] = packh2(ee_w2[(2 * m) * 16 + o], ee_w2[(2 * m + 1) * 16 + o]);
    }
    for (int i = t; i < 4096; i += 512) {
        int o = i >> 5, m = i & 31, k0 = 2 * m, k1 = k0 + 1;
        float a = (k0 < 63) ? cb_w1[k0 * 128 + o] : 0.f;
        float c = (k1 < 63) ? cb_w1[k1 * 128 + o] : 0.f;
        s_tile[O_CB1 + i] = packh2(a, c);
    }
    for (int i = t; i < 4096; i += 512) {
        int o = i >> 6, m = i & 63;
        s_tile[O_CB2 + i] = packh2(cb_w2[(2 * m) * 64 + o], cb_w2[(2 * m + 1) * 64 + o]);
    }
    float* bias = (float*)(s_tile + O_BIAS);
    if (t < 64) bias[t] = pe_b1[t];
    if (t < 64) bias[64 + t] = pe_b2[t];
    if (t < 32) bias[128 + t] = ee_b1[t];
    if (t < 16) bias[160 + t] = ee_b2[t];
    if (t < 128) bias[176 + t] = cb_b1[t];
    if (t < 64) bias[304 + t] = cb_b2[t];
    if (t < 32) bias[368 + t] = role_emb[t];
    // head weights (persistent tail region)
    if (t < 32)        s_hw[t]        = packh2(th_w[2 * t], th_w[2 * t + 1]);
    else if (t < 64)  { int m = t - 32;  s_hw[32 + m]  = packh2(an_w[2 * m], an_w[2 * m + 1]); }
    else if (t < 96)  { int m = t - 64;  s_hw[64 + m]  = packh2(sh_w[4 * m], sh_w[4 * m + 2]); }
    else if (t < 128) { int m = t - 96;  s_hw[96 + m]  = packh2(sh_w[4 * m + 1], sh_w[4 * m + 3]); }
    else if (t < 160) { int m = t - 128; s_hw[128 + m] = packh2(bo_w[4 * m], bo_w[4 * m + 2]); }
    else if (t < 192) { int m = t - 160; s_hw[160 + m] = packh2(bo_w[4 * m + 1], bo_w[4 * m + 3]); }
    if (t == 0) {
        s_hb[0] = th_b[0]; s_hb[1] = an_b[0];
        s_hb[2] = sh_b[0]; s_hb[3] = sh_b[1];
        s_hb[4] = bo_b[0]; s_hb[5] = bo_b[1];
        s_hb[6] = fmaxf(__expf(logstd[0]), 0.05f);
        s_hb[7] = fmaxf(__expf(logstd[1]), 0.05f);
    }
    if (t < 32) s_h32[t] = 0u;  // h0 = 0 (f16 pairs)
    __syncthreads();

    // ---------------- phase 0: encoders; pair (2s, 2s+1) handles step s ----------------
    {
        const int s = t >> 1;
        const int e = t & 1;
        const long long row = (long long)b * Sn + s;

        // A (e=0): entity encoders + command input pack
        unsigned int cpp[32];
        if (e == 0) {
            float lat[32];
            #pragma unroll 1
            for (int src = 0; src < 3; src++) {
                const float* xp = (src == 0) ? (tm_obs + row * 13) : (en_obs + row * 26 + (src - 1) * 13);
                unsigned int xpr[8];
                #pragma unroll
                for (int m = 0; m < 8; m++) {
                    int k0 = 2 * m, k1 = k0 + 1;
                    xpr[m] = packh2((k0 < 13) ? xp[k0] : 0.f, (k1 < 13) ? xp[k1] : 0.f);
                }
                unsigned int e1[16];
                #pragma unroll
                for (int o2 = 0; o2 < 16; o2++) {
                    float a0 = bias[128 + 2 * o2], a1 = bias[128 + 2 * o2 + 1];
                    const unsigned int* w0 = s_tile + O_EE1 + (2 * o2) * 8;
                    #pragma unroll
                    for (int m = 0; m < 8; m++) { a0 = dot2(xpr[m], w0[m], a0); a1 = dot2(xpr[m], w0[8 + m], a1); }
                    e1[o2] = packh2(fmaxf(a0, 0.f), fmaxf(a1, 0.f));
                }
                #pragma unroll
                for (int o = 0; o < 16; o++) {
                    float a0 = bias[160 + o];
                    const unsigned int* w0 = s_tile + O_EE2 + o * 16;
                    #pragma unroll
                    for (int m = 0; m < 16; m++) a0 = dot2(e1[m], w0[m], a0);
                    if (src == 0) lat[o] = a0;
                    else if (src == 1) lat[16 + o] = a0;
                    else lat[16 + o] = fmaxf(lat[16 + o], a0);
                }
            }
            const float* sp = self_obs + row * 15;
            const int rid = role_ids[row];
            const float* rvec = bias + 368 + rid * 16;
            #pragma unroll
            for (int m = 0; m < 32; m++) {
                int k0 = 2 * m, k1 = k0 + 1;
                float a = (k0 < 15) ? sp[k0] : (k0 < 31) ? lat[k0 - 15] : (k0 < 47) ? lat[16 + k0 - 31] : rvec[k0 - 47];
                float c = (k1 < 15) ? sp[k1] : (k1 < 31) ? lat[k1 - 15] : (k1 < 47) ? lat[16 + k1 - 31]
                                                                       : (k1 < 63) ? rvec[k1 - 47] : 0.f;
                cpp[m] = packh2(a, c);
            }
        }
        // broadcast cpp A -> B
        #pragma unroll
        for (int m = 0; m < 32; m++) {
            unsigned int v = __shfl_xor(cpp[m], 1);
            if (e) cpp[m] = v;
        }
        // cmd L1 (63->128 relu): each thread computes its 64-output half (32 pairs)
        unsigned int c1h[32];
        #pragma unroll
        for (int o2 = 0; o2 < 32; o2++) {
            const int o2g = e * 32 + o2;
            float a0 = bias[176 + 2 * o2g], a1 = bias[176 + 2 * o2g + 1];
            const unsigned int* w0 = s_tile + O_CB1 + (2 * o2g) * 32;
            #pragma unroll
            for (int m = 0; m < 32; m++) { a0 = dot2(cpp[m], w0[m], a0); a1 = dot2(cpp[m], w0[32 + m], a1); }
            c1h[o2] = packh2(fmaxf(a0, 0.f), fmaxf(a1, 0.f));
        }
        unsigned int c1o[32];
        #pragma unroll
        for (int m = 0; m < 32; m++) c1o[m] = __shfl_xor(c1h[m], 1);
        // cmd L2 (128->64 relu): each thread computes 32 outputs (16 pairs)
        unsigned int resc[16];
        {
            const int ob = e * 32;        // own c1 pairs base (u32 index into full c1)
            const int tb = 32 - ob;       // other half base
            #pragma unroll
            for (int o2 = 0; o2 < 16; o2++) {
                const int o2g = e * 16 + o2;
                float a0 = bias[304 + 2 * o2g], a1 = bias[304 + 2 * o2g + 1];
                const unsigned int* w0 = s_tile + O_CB2 + (2 * o2g) * 64;
                #pragma unroll
                for (int m = 0; m < 32; m++) { a0 = dot2(c1h[m], w0[ob + m], a0); a1 = dot2(c1h[m], w0[64 + ob + m], a1); }
                #pragma unroll
                for (int m = 0; m < 32; m++) { a0 = dot2(c1o[m], w0[tb + m], a0); a1 = dot2(c1o[m], w0[64 + tb + m], a1); }
                resc[o2] = packh2(fmaxf(a0, 0.f), fmaxf(a1, 0.f));
            }
        }
        // B (e=1): pilot encoder
        unsigned int resp[32];
        if (e == 1) {
            unsigned int inp[12];
            {
                const float* sp = self_obs + row * 15;
                const float* cp = cp_obs + row * 6;
                #pragma unroll
                for (int m = 0; m < 12; m++) {
                    int k0 = 2 * m, k1 = k0 + 1;
                    float a = (k0 < 15) ? sp[k0] : ((k0 < 21) ? cp[k0 - 15] : 0.f);
                    float c = (k1 < 15) ? sp[k1] : ((k1 < 21) ? cp[k1 - 15] : 0.f);
                    inp[m] = packh2(a, c);
                }
            }
            unsigned int r1p[32];
            #pragma unroll
            for (int o2 = 0; o2 < 32; o2++) {
                float a0 = bias[2 * o2], a1 = bias[2 * o2 + 1];
                const unsigned int* w0 = s_tile + O_PE1 + (2 * o2) * 12;
                #pragma unroll
                for (int m = 0; m < 12; m++) { a0 = dot2(inp[m], w0[m], a0); a1 = dot2(inp[m], w0[12 + m], a1); }
                r1p[o2] = packh2(fmaxf(a0, 0.f), fmaxf(a1, 0.f));
            }
            #pragma unroll
            for (int o2 = 0; o2 < 32; o2++) {
                float a0 = bias[64 + 2 * o2], a1 = bias[64 + 2 * o2 + 1];
                const unsigned int* w0 = s_tile + O_PE2 + (2 * o2) * 32;
                #pragma unroll
                for (int m = 0; m < 32; m++) { a0 = dot2(r1p[m], w0[m], a0); a1 = dot2(r1p[m], w0[32 + m], a1); }
                resp[o2] = packh2(fmaxf(a0, 0.f), fmaxf(a1, 0.f));
            }
        }
        __syncthreads();  // all phase-0 weight reads complete block-wide
        // row tile overwrites weights: u32 [0..31]=pilot, [32..63]=cmd
        uint4* rt4 = reinterpret_cast<uint4*>(s_tile + s * 64);
        if (e == 0) {
            #pragma unroll
            for (int q = 0; q < 4; q++)
                rt4[8 + q] = make_uint4(resc[4 * q], resc[4 * q + 1], resc[4 * q + 2], resc[4 * q + 3]);
        } else {
            #pragma unroll
            for (int q = 0; q < 8; q++)
                rt4[q] = make_uint4(resp[4 * q], resp[4 * q + 1], resp[4 * q + 2], resp[4 * q + 3]);
            #pragma unroll
            for (int q = 0; q < 4; q++)
                rt4[12 + q] = make_uint4(resc[4 * q], resc[4 * q + 1], resc[4 * q + 2], resc[4 * q + 3]);
        }
    }

    // ---------------- LSTM weights: gate g = t>>1 owns K-half e = t&1 ----------------
    const int g = t >> 1;
    const int e = t & 1;
    unsigned int wih[32], whh[16];
    #pragma unroll
    for (int j = 0; j < 32; j++) {
        int m = e * 32 + j;
        wih[j] = packh2(ih_w[(2 * m) * 256 + g], ih_w[(2 * m + 1) * 256 + g]);
    }
    #pragma unroll
    for (int j = 0; j < 16; j++) {
        int m = e * 16 + j;
        whh[j] = packh2(hh_w[(2 * m) * 256 + g], hh_w[(2 * m + 1) * 256 + g]);
    }
    const float bias_t = (e == 0) ? (ih_b[g] + hh_b[g]) : 0.f;
    __syncthreads();  // row tile ready

    // ---------------- LSTM over S ----------------
    const int grp = g >> 6;
    float c = 0.f, h = 0.f, i_act = 0.f;
    #pragma unroll 1
    for (int s = 0; s < Sn; s++) {
        float acc = bias_t;
        const uint4* rq = reinterpret_cast<const uint4*>(s_tile + s * 64) + e * 8;
        #pragma unroll
        for (int q = 0; q < 8; q++) {
            uint4 rv = rq[q];
            acc = dot2(rv.x, wih[4 * q + 0], acc);
            acc = dot2(rv.y, wih[4 * q + 1], acc);
            acc = dot2(rv.z, wih[4 * q + 2], acc);
            acc = dot2(rv.w, wih[4 * q + 3], acc);
        }
        const uint4* hq = reinterpret_cast<const uint4*>(s_h32) + e * 4;
        #pragma unroll
        for (int q = 0; q < 4; q++) {
            uint4 hv = hq[q];
            acc = dot2(hv.x, whh[4 * q + 0], acc);
            acc = dot2(hv.y, whh[4 * q + 1], acc);
            acc = dot2(hv.z, whh[4 * q + 2], acc);
            acc = dot2(hv.w, whh[4 * q + 3], acc);
        }
        float tot = acc + __shfl_xor(acc, 1);  // pair-sum: both halves
        if (e == 0) {
            float act = (grp == 2) ? tanhf_(tot) : sigmoidf_(tot);
            if (grp == 0) i_act = act; else s_g[g - 64] = act;
        }
        __syncthreads();
        if (e == 0 && g < 64) {
            float f_ = s_g[g], g_ = s_g[64 + g], o_ = s_g[128 + g];
            c = f_ * c + i_act * g_;
            h = o_ * tanhf_(c);
            float hnext = __shfl_down(h, 2);  // pair (g, g+1) -> threads (2g, 2g+2), same wave
            if ((g & 1) == 0) {
                unsigned int hp = packh2(h, hnext);
                s_h32[g >> 1] = hp;                                  // for next step's hh-dot
                s_tile[s * 64 + (((g >> 1) + s) & 31)] = hp;         // h history (row s is dead)
            }
        }
        __syncthreads();
    }

    // ---------------- heads for all steps (from h history in tile) ----------------
    {
        const int w = t >> 6, l = t & 63;
        const int m0 = (l & 7) * 4;
        const int j0 = l & 7;
        #pragma unroll 1
        for (int p = 0; p < 4; p++) {
            int s = w * 32 + p * 8 + (l >> 3);
            float ath = 0.f, aan = 0.f, as0 = 0.f, as1 = 0.f, ab0 = 0.f, ab1 = 0.f;
            #pragma unroll
            for (int j = 0; j < 4; j++) {
                int m = m0 + j;
                unsigned int hv = s_tile[s * 64 + ((m + s) & 31)];
                ath = dot2(hv, s_hw[m], ath);
                aan = dot2(hv, s_hw[32 + m], aan);
                as0 = dot2(hv, s_hw[64 + m], as0);
                as1 = dot2(hv, s_hw[96 + m], as1);
                ab0 = dot2(hv, s_hw[128 + m], ab0);
                ab1 = dot2(hv, s_hw[160 + m], ab1);
            }
            #pragma unroll
            for (int d = 1; d < 8; d <<= 1) {
                ath += __shfl_xor(ath, d); aan += __shfl_xor(aan, d);
                as0 += __shfl_xor(as0, d); as1 += __shfl_xor(as1, d);
                ab0 += __shfl_xor(ab0, d); ab1 += __shfl_xor(ab1, d);
            }
            long long row = (long long)b * Sn + s;
            if (j0 == 0)      out[row] = sigmoidf_(ath + s_hb[0]);
            else if (j0 == 1) out[BSn + row] = tanhf_(aan + s_hb[1]);
            else if (j0 == 2) out[2 * BSn + 2 * row] = s_hb[6];
            else if (j0 == 3) out[2 * BSn + 2 * row + 1] = s_hb[7];
            else if (j0 == 4) out[4 * BSn + 2 * row] = as0 + s_hb[2];
            else if (j0 == 5) out[4 * BSn + 2 * row + 1] = as1 + s_hb[3];
            else if (j0 == 6) out[6 * BSn + 2 * row] = ab0 + s_hb[4];
            else              out[6 * BSn + 2 * row + 1] = ab1 + s_hb[5];
        }
    }

    if (e == 0 && g < 64) {
        float* hn = out + 8 * BSn;
        float* cn = hn + (long long)Bn * 64;
        hn[(long long)b * 64 + g] = h;
        cn[(long long)b * 64 + g] = c;
    }
}

extern "C" void kernel_launch(void* const* d_in, const int* in_sizes, int n_in,
                              void* d_out, int out_size, void* d_ws, size_t ws_size,
                              hipStream_t stream)
{
    (void)in_sizes; (void)n_in; (void)out_size; (void)d_ws; (void)ws_size;
    k_fused<<<Bn, 512, 0, stream>>>(
        (const float*)d_in[0], (const float*)d_in[1], (const float*)d_in[2],
        (const float*)d_in[3], (const int*)d_in[4],
        (const float*)d_in[5], (const float*)d_in[6], (const float*)d_in[7], (const float*)d_in[8],
        (const float*)d_in[9],
        (const float*)d_in[10], (const float*)d_in[11], (const float*)d_in[12], (const float*)d_in[13],
        (const float*)d_in[14], (const float*)d_in[15], (const float*)d_in[16], (const float*)d_in[17],
        (const float*)d_in[18], (const float*)d_in[19], (const float*)d_in[20], (const float*)d_in[21],
        (const float*)d_in[22], (const float*)d_in[23], (const float*)d_in[24], (const float*)d_in[25],
        (const float*)d_in[26], (const float*)d_in[27], (const float*)d_in[28], (const float*)d_in[29],
        (const float*)d_in[30], (float*)d_out);
}